// Round 3
// baseline (245.645 us; speedup 1.0000x reference)
//
#include <hip/hip_runtime.h>
#include <math.h>

#define IC 64
#define OC 128
#define HH 56
#define WW 56
#define BATCH 16
#define HP 58              // padded spatial
#define NPIX (BATCH*HH*WW) // 50176
#define SPAN 576
#define TSIZE 8
#define VBLOCKS 112        // vote blocks; 112 * 448 = 50176
#define PADBLK 211         // pad covers 16*58*58 = 53824 pixels
#define NBLK_PREP (PADBLK + OC + VBLOCKS)   // 211 + 128 + 112 = 451

typedef unsigned short ushort_t;
typedef unsigned int uint_t;
typedef __attribute__((ext_vector_type(8))) __bf16 bf16x8;
typedef __attribute__((ext_vector_type(4))) float f32x4;

__device__ __forceinline__ ushort_t bf16_rne(float f) {
  uint_t u = __builtin_bit_cast(uint_t, f);
  u += 0x7FFFu + ((u >> 16) & 1u);
  return (ushort_t)(u >> 16);
}

// ---------------- kernel 1: fused prep (pad | w2row | vote) ------------------
// blocks [0,211): NCHW fp32 -> padded NHWC bf16
// blocks [211,339): per-OC-row dot/norm -> rbucket + bf16 (tap,c)-major repack
// blocks [339,451): patch voting, per-block histogram -> hist_partial (no atomics)
__global__ void prep_kernel(const float* __restrict__ x, const float* __restrict__ kernels,
                            const float* __restrict__ a, const float* __restrict__ bptr,
                            ushort_t* __restrict__ xpad, ushort_t* __restrict__ w2,
                            int* __restrict__ rbucket, int* __restrict__ hist_partial) {
  __shared__ float red0[256], red1[256];
  __shared__ int hist[TSIZE];
  const int bx = blockIdx.x, t = threadIdx.x;

  if (bx < PADBLK) {
    // ---- pad role ----
    int idx = bx * 256 + t;
    if (idx >= BATCH * HP * HP) return;
    int b = idx / (HP * HP);
    int rem = idx % (HP * HP);
    int y = rem / HP, xw = rem % HP;
    int h = y - 1, w = xw - 1;
    bool inb = ((unsigned)h < (unsigned)HH) && ((unsigned)w < (unsigned)WW);
    int off = inb ? (h * WW + w) : 0;
    const float* src = x + (size_t)b * IC * HH * WW + off;
    uint_t* dst = (uint_t*)(xpad + (size_t)idx * IC);
    #pragma unroll
    for (int c2 = 0; c2 < IC / 2; ++c2) {
      float f0 = inb ? src[(2 * c2) * (HH * WW)] : 0.0f;
      float f1 = inb ? src[(2 * c2 + 1) * (HH * WW)] : 0.0f;
      dst[c2] = (uint_t)bf16_rne(f0) | ((uint_t)bf16_rne(f1) << 16);
    }
  } else if (bx < PADBLK + OC) {
    // ---- w2row role ----
    const int r = bx - PADBLK;
    const float* row = kernels + (size_t)r * SPAN;
    float d = 0.0f, n2 = 0.0f;
    #pragma unroll
    for (int k0 = 0; k0 < 3; ++k0) {
      int k = k0 * 256 + t;
      if (k < SPAN) { float kv = row[k]; d += kv * a[k]; n2 += kv * kv; }
    }
    red0[t] = d; red1[t] = n2;
    __syncthreads();
    for (int s = 128; s > 0; s >>= 1) {
      if (t < s) { red0[t] += red0[t + s]; red1[t] += red1[t + s]; }
      __syncthreads();
    }
    if (t == 0) {
      float hk = red0[0], p = red1[0];
      #pragma unroll
      for (int i = 0; i < 5; ++i) { hk += p * a[SPAN + i]; p = p * p; }
      int hi = (int)floorf((hk + bptr[0]) / 2.5f);
      int rr = hi % TSIZE;
      if (rr < 0) rr = -rr;
      rbucket[r] = rr;
    }
    #pragma unroll
    for (int j0 = 0; j0 < 3; ++j0) {
      int j = j0 * 256 + t;
      if (j < SPAN) {
        int tap = j >> 6, c = j & 63;
        w2[(size_t)r * SPAN + j] = bf16_rne(row[c * 9 + tap]);
      }
    }
  } else {
    // ---- vote role: 448 pixels per block, 7 chunks of (64 px x 4 chan-quarters) ----
    const int vb = bx - (PADBLK + OC);
    if (t < TSIZE) hist[t] = 0;
    const int pl = t & 63, cq = t >> 6;
    const float tail = 0.5f * (a[576] + a[577] + a[578] + a[579] + a[580]);
    const float bval = bptr[0];
    __syncthreads();
    for (int it = 0; it < 7; ++it) {
      int n = vb * 448 + it * 64 + pl;
      int b = n / (HH * WW);
      int rem = n % (HH * WW);
      int h = rem / WW, w = rem % WW;
      const float* xb = x + (size_t)b * IC * HH * WW;
      float s = 0.0f;
      for (int c = cq * 16; c < cq * 16 + 16; ++c) {
        const float* xc = xb + c * (HH * WW);
        const float* ac = a + c * 9;
        #pragma unroll
        for (int kh = 0; kh < 3; ++kh) {
          int y = h + kh - 1;
          if ((unsigned)y < (unsigned)HH) {
            #pragma unroll
            for (int kw = 0; kw < 3; ++kw) {
              int xx = w + kw - 1;
              if ((unsigned)xx < (unsigned)WW) s += ac[kh * 3 + kw] * xc[y * WW + xx];
            }
          }
        }
      }
      red0[t] = s;
      __syncthreads();
      if (t < 64) {
        float v = red0[t] + red0[t + 64] + red0[t + 128] + red0[t + 192];
        int hi = (int)floorf((v + tail + bval) / 2.5f);
        int r = hi % TSIZE;
        if (r < 0) r = -r;
        atomicAdd(&hist[r], 1);   // LDS atomic, cheap
      }
      __syncthreads();
    }
    if (t < TSIZE) hist_partial[vb * TSIZE + t] = hist[t];
  }
}

// ---------------- kernel 2: implicit GEMM, 128x64 tile, BK=64 (one tap) ------
// C[128, 50176] = W2[128,576] @ P[576,50176];  P gathered from padded NHWC bf16.
// Bucket histogram reduced per-block from hist_partial (no global atomics);
// factor applied in fp32 epilogue.
__global__ __launch_bounds__(256, 4)
void gemm_kernel(const ushort_t* __restrict__ w2, const ushort_t* __restrict__ xpad,
                 const int* __restrict__ hist_partial, const int* __restrict__ rbucket,
                 float* __restrict__ out) {
  __shared__ ushort_t As[128 * 64];   // 16 KB
  __shared__ ushort_t Bs[64 * 64];    //  8 KB
  __shared__ float factor_s[OC];
  __shared__ int counts_s[TSIZE];
  __shared__ int cnt_w[4];
  const int tid = threadIdx.x;
  const int wave = tid >> 6, lane = tid & 63;
  const int n0 = blockIdx.x * 64;
  const int wm = wave * 32;           // wave M-offset (32 oc rows per wave)

  const int srow = lane >> 3;         // 0..7
  const int sch = (lane & 7) ^ srow;  // swizzled global chunk for this lane

  int agbase[4], bgbase[2];
  #pragma unroll
  for (int i = 0; i < 4; ++i) {
    int row = wm + i * 8 + srow;
    agbase[i] = row * SPAN + sch * 8;
  }
  #pragma unroll
  for (int i = 0; i < 2; ++i) {
    int brow = wave * 16 + i * 8 + srow;
    int n = n0 + brow;
    int b = n / (HH * WW);
    int rem = n % (HH * WW);
    int h = rem / WW, w = rem % WW;
    bgbase[i] = ((b * HP + h) * HP + w) * IC + sch * 8;
  }

  f32x4 acc[2][4] = {};

  for (int tap = 0; tap < 9; ++tap) {
    const int kh = tap / 3, kw = tap % 3;
    const int toffA = tap * 64;
    const int toffB = (kh * HP + kw) * IC;
    __syncthreads();  // previous tile consumed
    #pragma unroll
    for (int i = 0; i < 4; ++i)
      __builtin_amdgcn_global_load_lds(
          (const __attribute__((address_space(1))) void*)(w2 + agbase[i] + toffA),
          (__attribute__((address_space(3))) void*)(As + (wm + i * 8) * 64), 16, 0, 0);
    #pragma unroll
    for (int i = 0; i < 2; ++i)
      __builtin_amdgcn_global_load_lds(
          (const __attribute__((address_space(1))) void*)(xpad + bgbase[i] + toffB),
          (__attribute__((address_space(3))) void*)(Bs + (wave * 16 + i * 8) * 64), 16, 0, 0);
    __syncthreads();  // staging drained
    #pragma unroll
    for (int kk = 0; kk < 2; ++kk) {
      const int jf = kk * 4 + (lane >> 4);
      bf16x8 af[2], bfr[4];
      #pragma unroll
      for (int m = 0; m < 2; ++m) {
        int row = wm + m * 16 + (lane & 15);
        int slot = row * 8 + (jf ^ (row & 7));
        af[m] = *(const bf16x8*)(As + slot * 8);
      }
      #pragma unroll
      for (int n = 0; n < 4; ++n) {
        int col = n * 16 + (lane & 15);
        int slot = col * 8 + (jf ^ (col & 7));
        bfr[n] = *(const bf16x8*)(Bs + slot * 8);
      }
      #pragma unroll
      for (int m = 0; m < 2; ++m)
        #pragma unroll
        for (int n = 0; n < 4; ++n)
          acc[m][n] = __builtin_amdgcn_mfma_f32_16x16x32_bf16(af[m], bfr[n], acc[m][n], 0, 0, 0);
    }
  }

  // ---- reduce hist_partial -> counts_s (no global atomics anywhere) --------
  if (tid < TSIZE) counts_s[tid] = 0;
  __syncthreads();
  {
    int bin = tid >> 5;           // 8 bins x 32 summers
    int s = 0;
    for (int k = (tid & 31); k < VBLOCKS; k += 32) s += hist_partial[k * TSIZE + bin];
    atomicAdd(&counts_s[bin], s); // LDS atomic
  }
  __syncthreads();
  // ---- argmax + row mask + count via ballot --------------------------------
  int best = counts_s[0], bi = 0;
  #pragma unroll
  for (int i = 1; i < TSIZE; ++i) { int c = counts_s[i]; if (c > best) { best = c; bi = i; } }
  int isin = (tid < OC) ? ((rbucket[tid] == bi) ? 1 : 0) : 0;
  unsigned long long bal = __ballot(isin != 0);
  if (lane == 0) cnt_w[wave] = __popcll(bal);
  __syncthreads();
  int cnt = cnt_w[0] + cnt_w[1] + cnt_w[2] + cnt_w[3];
  if (tid < OC)
    factor_s[tid] = (cnt > 0) ? (isin ? 128.0f / (float)cnt : 0.0f) : 1.0f;
  __syncthreads();

  // ---- epilogue: C/D layout col=lane&15 (pixel), row=(lane>>4)*4+r (oc) -----
  #pragma unroll
  for (int n = 0; n < 4; ++n) {
    int np = n0 + n * 16 + (lane & 15);
    int b = np / (HH * WW);
    int rem = np % (HH * WW);
    float* obase = out + ((size_t)b * OC) * (HH * WW) + rem;
    #pragma unroll
    for (int m = 0; m < 2; ++m) {
      int ocb = wm + m * 16 + (lane >> 4) * 4;
      #pragma unroll
      for (int r = 0; r < 4; ++r) {
        obase[(size_t)(ocb + r) * (HH * WW)] = acc[m][n][r] * factor_s[ocb + r];
      }
    }
  }
}

extern "C" void kernel_launch(void* const* d_in, const int* in_sizes, int n_in,
                              void* d_out, int out_size, void* d_ws, size_t ws_size,
                              hipStream_t stream) {
  (void)in_sizes; (void)n_in; (void)out_size; (void)ws_size;
  const float* x = (const float*)d_in[0];       // [16,64,56,56]
  const float* kernels = (const float*)d_in[1]; // [128,576]
  const float* a = (const float*)d_in[2];       // [581]
  const float* b = (const float*)d_in[3];       // scalar
  float* out = (float*)d_out;                   // [16,128,56,56] fp32

  char* ws = (char*)d_ws;
  int* rbucket = (int*)ws;                          // 512 B
  int* hist_partial = (int*)(ws + 512);             // 112*8*4 = 3584 B
  ushort_t* w2 = (ushort_t*)(ws + 8192);            // 147456 B
  ushort_t* xpad = (ushort_t*)(ws + 8192 + 147456); // 6,889,472 B

  prep_kernel<<<NBLK_PREP, 256, 0, stream>>>(x, kernels, a, b, xpad, w2, rbucket, hist_partial);
  gemm_kernel<<<NPIX / 64, 256, 0, stream>>>(w2, xpad, hist_partial, rbucket, out);
}

// Round 4
// 220.133 us; speedup vs baseline: 1.1159x; 1.1159x over previous
//
#include <hip/hip_runtime.h>
#include <math.h>

#define IC 64
#define OC 128
#define HH 56
#define WW 56
#define BATCH 16
#define HP 58              // padded spatial
#define HW (HH*WW)         // 3136
#define NPIX (BATCH*HW)    // 50176
#define SPAN 576
#define TSIZE 8
#define VBLOCKS 196        // stage2 blocks: 196*256 = 50176

typedef unsigned short ushort_t;
typedef unsigned int uint_t;
typedef __attribute__((ext_vector_type(8))) __bf16 bf16x8;
typedef __attribute__((ext_vector_type(4))) float f32x4;

__device__ __forceinline__ ushort_t bf16_rne(float f) {
  uint_t u = __builtin_bit_cast(uint_t, f);
  u += 0x7FFFu + ((u >> 16) & 1u);
  return (ushort_t)(u >> 16);
}

// ---- kernel 1: pad (NCHW fp32 -> padded NHWC bf16) + vote stage 1 -----------
// t[b,tap,pix] = sum_c a[c*9+tap] * x[b,c,pix]   (streaming, no re-read of x)
__global__ void padvote1_kernel(const float* __restrict__ x, const float* __restrict__ a,
                                ushort_t* __restrict__ xpad, float* __restrict__ tbuf) {
  __shared__ float as_[SPAN];
  const int t = threadIdx.x;
  #pragma unroll
  for (int j0 = 0; j0 < 3; ++j0) {
    int j = j0 * 256 + t;
    if (j < SPAN) as_[j] = a[j];
  }
  __syncthreads();
  int idx = blockIdx.x * 256 + t;
  if (idx >= BATCH * HP * HP) return;
  int b = idx / (HP * HP);
  int rem = idx % (HP * HP);
  int y = rem / HP, xw = rem % HP;
  int h = y - 1, w = xw - 1;
  bool inb = ((unsigned)h < (unsigned)HH) && ((unsigned)w < (unsigned)WW);
  const float* src = x + (size_t)b * IC * HW + (inb ? h * WW + w : 0);
  uint_t* dst = (uint_t*)(xpad + (size_t)idx * IC);
  float t9[9] = {0, 0, 0, 0, 0, 0, 0, 0, 0};
  #pragma unroll
  for (int c2 = 0; c2 < IC / 2; ++c2) {
    float f0 = inb ? src[(2 * c2) * HW] : 0.0f;
    float f1 = inb ? src[(2 * c2 + 1) * HW] : 0.0f;
    dst[c2] = (uint_t)bf16_rne(f0) | ((uint_t)bf16_rne(f1) << 16);
    #pragma unroll
    for (int tap = 0; tap < 9; ++tap)
      t9[tap] += as_[(2 * c2) * 9 + tap] * f0 + as_[(2 * c2 + 1) * 9 + tap] * f1;
  }
  if (inb) {
    int p = h * WW + w;
    float* tb = tbuf + ((size_t)b * 9) * HW + p;
    #pragma unroll
    for (int tap = 0; tap < 9; ++tap) tb[(size_t)tap * HW] = t9[tap];
  }
}

// ---- kernel 2: vote stage 2 — 9-tap gather of t, bucket, per-block hist -----
__global__ void vote2_kernel(const float* __restrict__ tbuf, const float* __restrict__ a,
                             const float* __restrict__ bptr, int* __restrict__ hist_partial) {
  __shared__ int hist[TSIZE];
  const int t = threadIdx.x;
  if (t < TSIZE) hist[t] = 0;
  __syncthreads();
  int n = blockIdx.x * 256 + t;
  int b = n / HW, p = n % HW;
  int h = p / WW, w = p % WW;
  const float* tb = tbuf + ((size_t)b * 9) * HW;
  float v = 0.0f;
  #pragma unroll
  for (int kh = 0; kh < 3; ++kh) {
    int yy = h + kh - 1;
    if ((unsigned)yy < (unsigned)HH) {
      #pragma unroll
      for (int kw = 0; kw < 3; ++kw) {
        int xx = w + kw - 1;
        if ((unsigned)xx < (unsigned)WW) v += tb[(size_t)(kh * 3 + kw) * HW + yy * WW + xx];
      }
    }
  }
  float tail = 0.5f * (a[576] + a[577] + a[578] + a[579] + a[580]);
  int hi = (int)floorf((v + tail + bptr[0]) / 2.5f);
  int r = hi % TSIZE;
  if (r < 0) r = -r;
  atomicAdd(&hist[r], 1);   // LDS atomic, 8 bins
  __syncthreads();
  if (t < TSIZE) hist_partial[blockIdx.x * TSIZE + t] = hist[t];
}

// ---- kernel 3: per-row dot/norm -> rbucket + bf16 (tap,c)-major repack ------
__global__ void w2row_kernel(const float* __restrict__ kernels, const float* __restrict__ a,
                             const float* __restrict__ bptr, ushort_t* __restrict__ w2,
                             int* __restrict__ rbucket) {
  const int r = blockIdx.x, t = threadIdx.x;
  const float* row = kernels + (size_t)r * SPAN;
  float d = 0.0f, n2 = 0.0f;
  #pragma unroll
  for (int k0 = 0; k0 < 3; ++k0) {
    int k = k0 * 256 + t;
    if (k < SPAN) { float kv = row[k]; d += kv * a[k]; n2 += kv * kv; }
  }
  __shared__ float red0[256], red1[256];
  red0[t] = d; red1[t] = n2;
  __syncthreads();
  for (int s = 128; s > 0; s >>= 1) {
    if (t < s) { red0[t] += red0[t + s]; red1[t] += red1[t + s]; }
    __syncthreads();
  }
  if (t == 0) {
    float hk = red0[0], p = red1[0];
    #pragma unroll
    for (int i = 0; i < 5; ++i) { hk += p * a[SPAN + i]; p = p * p; }
    int hi = (int)floorf((hk + bptr[0]) / 2.5f);
    int rr = hi % TSIZE;
    if (rr < 0) rr = -rr;
    rbucket[r] = rr;
  }
  #pragma unroll
  for (int j0 = 0; j0 < 3; ++j0) {
    int j = j0 * 256 + t;
    if (j < SPAN) {
      int tap = j >> 6, c = j & 63;
      w2[(size_t)r * SPAN + j] = bf16_rne(row[c * 9 + tap]);
    }
  }
}

// ---- kernel 4: implicit GEMM, 128x64 tile, BK=64 (one tap) ------------------
__global__ __launch_bounds__(256, 4)
void gemm_kernel(const ushort_t* __restrict__ w2, const ushort_t* __restrict__ xpad,
                 const int* __restrict__ hist_partial, const int* __restrict__ rbucket,
                 float* __restrict__ out) {
  __shared__ ushort_t As[128 * 64];   // 16 KB
  __shared__ ushort_t Bs[64 * 64];    //  8 KB
  __shared__ float factor_s[OC];
  __shared__ int counts_s[TSIZE];
  __shared__ int cnt_w[4];
  const int tid = threadIdx.x;
  const int wave = tid >> 6, lane = tid & 63;
  const int n0 = blockIdx.x * 64;
  const int wm = wave * 32;

  const int srow = lane >> 3;
  const int sch = (lane & 7) ^ srow;

  int agbase[4], bgbase[2];
  #pragma unroll
  for (int i = 0; i < 4; ++i) {
    int row = wm + i * 8 + srow;
    agbase[i] = row * SPAN + sch * 8;
  }
  #pragma unroll
  for (int i = 0; i < 2; ++i) {
    int brow = wave * 16 + i * 8 + srow;
    int n = n0 + brow;
    int b = n / HW;
    int rem = n % HW;
    int h = rem / WW, w = rem % WW;
    bgbase[i] = ((b * HP + h) * HP + w) * IC + sch * 8;
  }

  f32x4 acc[2][4] = {};

  for (int tap = 0; tap < 9; ++tap) {
    const int kh = tap / 3, kw = tap % 3;
    const int toffA = tap * 64;
    const int toffB = (kh * HP + kw) * IC;
    __syncthreads();
    #pragma unroll
    for (int i = 0; i < 4; ++i)
      __builtin_amdgcn_global_load_lds(
          (const __attribute__((address_space(1))) void*)(w2 + agbase[i] + toffA),
          (__attribute__((address_space(3))) void*)(As + (wm + i * 8) * 64), 16, 0, 0);
    #pragma unroll
    for (int i = 0; i < 2; ++i)
      __builtin_amdgcn_global_load_lds(
          (const __attribute__((address_space(1))) void*)(xpad + bgbase[i] + toffB),
          (__attribute__((address_space(3))) void*)(Bs + (wave * 16 + i * 8) * 64), 16, 0, 0);
    __syncthreads();
    #pragma unroll
    for (int kk = 0; kk < 2; ++kk) {
      const int jf = kk * 4 + (lane >> 4);
      bf16x8 af[2], bfr[4];
      #pragma unroll
      for (int m = 0; m < 2; ++m) {
        int row = wm + m * 16 + (lane & 15);
        int slot = row * 8 + (jf ^ (row & 7));
        af[m] = *(const bf16x8*)(As + slot * 8);
      }
      #pragma unroll
      for (int n = 0; n < 4; ++n) {
        int col = n * 16 + (lane & 15);
        int slot = col * 8 + (jf ^ (col & 7));
        bfr[n] = *(const bf16x8*)(Bs + slot * 8);
      }
      #pragma unroll
      for (int m = 0; m < 2; ++m)
        #pragma unroll
        for (int n = 0; n < 4; ++n)
          acc[m][n] = __builtin_amdgcn_mfma_f32_16x16x32_bf16(af[m], bfr[n], acc[m][n], 0, 0, 0);
    }
  }

  // ---- reduce hist_partial -> counts_s ----
  if (tid < TSIZE) counts_s[tid] = 0;
  __syncthreads();
  {
    int bin = tid >> 5;
    int s = 0;
    for (int k = (tid & 31); k < VBLOCKS; k += 32) s += hist_partial[k * TSIZE + bin];
    atomicAdd(&counts_s[bin], s);
  }
  __syncthreads();
  int best = counts_s[0], bi = 0;
  #pragma unroll
  for (int i = 1; i < TSIZE; ++i) { int c = counts_s[i]; if (c > best) { best = c; bi = i; } }
  int isin = (tid < OC) ? ((rbucket[tid] == bi) ? 1 : 0) : 0;
  unsigned long long bal = __ballot(isin != 0);
  if (lane == 0) cnt_w[wave] = __popcll(bal);
  __syncthreads();
  int cnt = cnt_w[0] + cnt_w[1] + cnt_w[2] + cnt_w[3];
  if (tid < OC)
    factor_s[tid] = (cnt > 0) ? (isin ? 128.0f / (float)cnt : 0.0f) : 1.0f;
  __syncthreads();

  #pragma unroll
  for (int n = 0; n < 4; ++n) {
    int np = n0 + n * 16 + (lane & 15);
    int b = np / HW;
    int rem = np % HW;
    float* obase = out + ((size_t)b * OC) * HW + rem;
    #pragma unroll
    for (int m = 0; m < 2; ++m) {
      int ocb = wm + m * 16 + (lane >> 4) * 4;
      #pragma unroll
      for (int r = 0; r < 4; ++r) {
        obase[(size_t)(ocb + r) * HW] = acc[m][n][r] * factor_s[ocb + r];
      }
    }
  }
}

extern "C" void kernel_launch(void* const* d_in, const int* in_sizes, int n_in,
                              void* d_out, int out_size, void* d_ws, size_t ws_size,
                              hipStream_t stream) {
  (void)in_sizes; (void)n_in; (void)out_size; (void)ws_size;
  const float* x = (const float*)d_in[0];       // [16,64,56,56]
  const float* kernels = (const float*)d_in[1]; // [128,576]
  const float* a = (const float*)d_in[2];       // [581]
  const float* b = (const float*)d_in[3];       // scalar
  float* out = (float*)d_out;                   // [16,128,56,56] fp32

  char* ws = (char*)d_ws;
  int* rbucket = (int*)ws;                            // 512 B
  int* hist_partial = (int*)(ws + 512);               // 196*8*4 = 6272 B
  ushort_t* w2 = (ushort_t*)(ws + 8192);              // 147456 B
  float* tbuf = (float*)(ws + 8192 + 147456);         // 16*9*3136*4 = 1806336 B
  ushort_t* xpad = (ushort_t*)(ws + 8192 + 147456 + 1806336); // 6889472 B

  padvote1_kernel<<<211, 256, 0, stream>>>(x, a, xpad, tbuf);
  vote2_kernel<<<VBLOCKS, 256, 0, stream>>>(tbuf, a, b, hist_partial);
  w2row_kernel<<<OC, 256, 0, stream>>>(kernels, a, b, w2, rbucket);
  gemm_kernel<<<NPIX / 64, 256, 0, stream>>>(w2, xpad, hist_partial, rbucket, out);
}

// Round 5
// 121.948 us; speedup vs baseline: 2.0143x; 1.8051x over previous
//
#include <hip/hip_runtime.h>
#include <math.h>

#define IC 64
#define OC 128
#define HH 56
#define WW 56
#define BATCH 16
#define HP 58              // padded spatial
#define HW (HH*WW)         // 3136
#define NPIX (BATCH*HW)    // 50176
#define SPAN 576
#define TSIZE 8
#define VBLOCKS 196        // vote blocks: 196*256 = 50176

typedef unsigned short ushort_t;
typedef unsigned int uint_t;
typedef __attribute__((ext_vector_type(8))) __bf16 bf16x8;
typedef __attribute__((ext_vector_type(4))) float f32x4;

__device__ __forceinline__ ushort_t bf16_rne(float f) {
  uint_t u = __builtin_bit_cast(uint_t, f);
  u += 0x7FFFu + ((u >> 16) & 1u);
  return (ushort_t)(u >> 16);
}

// ---- kernel 1: NCHW fp32 -> padded NHWC bf16 (R2 form) ----------------------
__global__ void pad_kernel(const float* __restrict__ x, ushort_t* __restrict__ xpad) {
  int idx = blockIdx.x * 256 + threadIdx.x;
  if (idx >= BATCH * HP * HP) return;
  int b = idx / (HP * HP);
  int rem = idx % (HP * HP);
  int y = rem / HP, xw = rem % HP;
  int h = y - 1, w = xw - 1;
  bool inb = ((unsigned)h < (unsigned)HH) && ((unsigned)w < (unsigned)WW);
  const float* src = x + (size_t)b * IC * HW + (inb ? h * WW + w : 0);
  uint_t* dst = (uint_t*)(xpad + (size_t)idx * IC);
  #pragma unroll
  for (int c2 = 0; c2 < IC / 2; ++c2) {
    float f0 = inb ? src[(2 * c2) * HW] : 0.0f;
    float f1 = inb ? src[(2 * c2 + 1) * HW] : 0.0f;
    dst[c2] = (uint_t)bf16_rne(f0) | ((uint_t)bf16_rne(f1) << 16);
  }
}

// ---- kernel 2: vote stage 1 — t[b,tap,p] = sum_c a[c*9+tap]*x[b,c,p] --------
// Thread = pixel. Coalesced x loads; a[] via wave-uniform scalar loads.
__global__ __launch_bounds__(256)
void tstage_kernel(const float* __restrict__ x, const float* __restrict__ a,
                   float* __restrict__ tbuf) {
  int n = blockIdx.x * 256 + threadIdx.x;   // 196 blocks, exact
  int b = n / HW, p = n % HW;
  const float* xb = x + (size_t)b * IC * HW + p;
  float t9[9] = {0, 0, 0, 0, 0, 0, 0, 0, 0};
  #pragma unroll
  for (int c = 0; c < IC; ++c) {
    float xv = xb[(size_t)c * HW];
    #pragma unroll
    for (int tap = 0; tap < 9; ++tap) t9[tap] += a[c * 9 + tap] * xv;
  }
  float* tb = tbuf + (size_t)b * 9 * HW + p;
  #pragma unroll
  for (int tap = 0; tap < 9; ++tap) tb[(size_t)tap * HW] = t9[tap];
}

// ---- kernel 3: vote stage 2 — 9-tap gather of t, bucket, per-block hist -----
__global__ void vote2_kernel(const float* __restrict__ tbuf, const float* __restrict__ a,
                             const float* __restrict__ bptr, int* __restrict__ hist_partial) {
  __shared__ int hist[TSIZE];
  const int t = threadIdx.x;
  if (t < TSIZE) hist[t] = 0;
  __syncthreads();
  int n = blockIdx.x * 256 + t;
  int b = n / HW, p = n % HW;
  int h = p / WW, w = p % WW;
  const float* tb = tbuf + ((size_t)b * 9) * HW;
  float v = 0.0f;
  #pragma unroll
  for (int kh = 0; kh < 3; ++kh) {
    int yy = h + kh - 1;
    if ((unsigned)yy < (unsigned)HH) {
      #pragma unroll
      for (int kw = 0; kw < 3; ++kw) {
        int xx = w + kw - 1;
        if ((unsigned)xx < (unsigned)WW) v += tb[(size_t)(kh * 3 + kw) * HW + yy * WW + xx];
      }
    }
  }
  float tail = 0.5f * (a[576] + a[577] + a[578] + a[579] + a[580]);
  int hi = (int)floorf((v + tail + bptr[0]) / 2.5f);
  int r = hi % TSIZE;
  if (r < 0) r = -r;
  atomicAdd(&hist[r], 1);   // LDS atomic, 8 bins
  __syncthreads();
  if (t < TSIZE) hist_partial[blockIdx.x * TSIZE + t] = hist[t];
}

// ---- kernel 4: per-row dot/norm -> rbucket + bf16 (tap,c)-major repack ------
__global__ void w2row_kernel(const float* __restrict__ kernels, const float* __restrict__ a,
                             const float* __restrict__ bptr, ushort_t* __restrict__ w2,
                             int* __restrict__ rbucket) {
  const int r = blockIdx.x, t = threadIdx.x;
  const float* row = kernels + (size_t)r * SPAN;
  float d = 0.0f, n2 = 0.0f;
  #pragma unroll
  for (int k0 = 0; k0 < 3; ++k0) {
    int k = k0 * 256 + t;
    if (k < SPAN) { float kv = row[k]; d += kv * a[k]; n2 += kv * kv; }
  }
  __shared__ float red0[256], red1[256];
  red0[t] = d; red1[t] = n2;
  __syncthreads();
  for (int s = 128; s > 0; s >>= 1) {
    if (t < s) { red0[t] += red0[t + s]; red1[t] += red1[t + s]; }
    __syncthreads();
  }
  if (t == 0) {
    float hk = red0[0], p = red1[0];
    #pragma unroll
    for (int i = 0; i < 5; ++i) { hk += p * a[SPAN + i]; p = p * p; }
    int hi = (int)floorf((hk + bptr[0]) / 2.5f);
    int rr = hi % TSIZE;
    if (rr < 0) rr = -rr;
    rbucket[r] = rr;
  }
  #pragma unroll
  for (int j0 = 0; j0 < 3; ++j0) {
    int j = j0 * 256 + t;
    if (j < SPAN) {
      int tap = j >> 6, c = j & 63;
      w2[(size_t)r * SPAN + j] = bf16_rne(row[c * 9 + tap]);
    }
  }
}

// ---- kernel 5: implicit GEMM, 128x64 tile, BK=64 (one tap) ------------------
__global__ __launch_bounds__(256, 4)
void gemm_kernel(const ushort_t* __restrict__ w2, const ushort_t* __restrict__ xpad,
                 const int* __restrict__ hist_partial, const int* __restrict__ rbucket,
                 float* __restrict__ out) {
  __shared__ ushort_t As[128 * 64];   // 16 KB
  __shared__ ushort_t Bs[64 * 64];    //  8 KB
  __shared__ float factor_s[OC];
  __shared__ int counts_s[TSIZE];
  __shared__ int cnt_w[4];
  const int tid = threadIdx.x;
  const int wave = tid >> 6, lane = tid & 63;
  const int n0 = blockIdx.x * 64;
  const int wm = wave * 32;

  const int srow = lane >> 3;
  const int sch = (lane & 7) ^ srow;

  int agbase[4], bgbase[2];
  #pragma unroll
  for (int i = 0; i < 4; ++i) {
    int row = wm + i * 8 + srow;
    agbase[i] = row * SPAN + sch * 8;
  }
  #pragma unroll
  for (int i = 0; i < 2; ++i) {
    int brow = wave * 16 + i * 8 + srow;
    int n = n0 + brow;
    int b = n / HW;
    int rem = n % HW;
    int h = rem / WW, w = rem % WW;
    bgbase[i] = ((b * HP + h) * HP + w) * IC + sch * 8;
  }

  f32x4 acc[2][4] = {};

  for (int tap = 0; tap < 9; ++tap) {
    const int kh = tap / 3, kw = tap % 3;
    const int toffA = tap * 64;
    const int toffB = (kh * HP + kw) * IC;
    __syncthreads();
    #pragma unroll
    for (int i = 0; i < 4; ++i)
      __builtin_amdgcn_global_load_lds(
          (const __attribute__((address_space(1))) void*)(w2 + agbase[i] + toffA),
          (__attribute__((address_space(3))) void*)(As + (wm + i * 8) * 64), 16, 0, 0);
    #pragma unroll
    for (int i = 0; i < 2; ++i)
      __builtin_amdgcn_global_load_lds(
          (const __attribute__((address_space(1))) void*)(xpad + bgbase[i] + toffB),
          (__attribute__((address_space(3))) void*)(Bs + (wave * 16 + i * 8) * 64), 16, 0, 0);
    __syncthreads();
    #pragma unroll
    for (int kk = 0; kk < 2; ++kk) {
      const int jf = kk * 4 + (lane >> 4);
      bf16x8 af[2], bfr[4];
      #pragma unroll
      for (int m = 0; m < 2; ++m) {
        int row = wm + m * 16 + (lane & 15);
        int slot = row * 8 + (jf ^ (row & 7));
        af[m] = *(const bf16x8*)(As + slot * 8);
      }
      #pragma unroll
      for (int n = 0; n < 4; ++n) {
        int col = n * 16 + (lane & 15);
        int slot = col * 8 + (jf ^ (col & 7));
        bfr[n] = *(const bf16x8*)(Bs + slot * 8);
      }
      #pragma unroll
      for (int m = 0; m < 2; ++m)
        #pragma unroll
        for (int n = 0; n < 4; ++n)
          acc[m][n] = __builtin_amdgcn_mfma_f32_16x16x32_bf16(af[m], bfr[n], acc[m][n], 0, 0, 0);
    }
  }

  // ---- reduce hist_partial -> counts_s ----
  if (tid < TSIZE) counts_s[tid] = 0;
  __syncthreads();
  {
    int bin = tid >> 5;
    int s = 0;
    for (int k = (tid & 31); k < VBLOCKS; k += 32) s += hist_partial[k * TSIZE + bin];
    atomicAdd(&counts_s[bin], s);
  }
  __syncthreads();
  int best = counts_s[0], bi = 0;
  #pragma unroll
  for (int i = 1; i < TSIZE; ++i) { int c = counts_s[i]; if (c > best) { best = c; bi = i; } }
  int isin = (tid < OC) ? ((rbucket[tid] == bi) ? 1 : 0) : 0;
  unsigned long long bal = __ballot(isin != 0);
  if (lane == 0) cnt_w[wave] = __popcll(bal);
  __syncthreads();
  int cnt = cnt_w[0] + cnt_w[1] + cnt_w[2] + cnt_w[3];
  if (tid < OC)
    factor_s[tid] = (cnt > 0) ? (isin ? 128.0f / (float)cnt : 0.0f) : 1.0f;
  __syncthreads();

  #pragma unroll
  for (int n = 0; n < 4; ++n) {
    int np = n0 + n * 16 + (lane & 15);
    int b = np / HW;
    int rem = np % HW;
    float* obase = out + ((size_t)b * OC) * HW + rem;
    #pragma unroll
    for (int m = 0; m < 2; ++m) {
      int ocb = wm + m * 16 + (lane >> 4) * 4;
      #pragma unroll
      for (int r = 0; r < 4; ++r) {
        obase[(size_t)(ocb + r) * HW] = acc[m][n][r] * factor_s[ocb + r];
      }
    }
  }
}

extern "C" void kernel_launch(void* const* d_in, const int* in_sizes, int n_in,
                              void* d_out, int out_size, void* d_ws, size_t ws_size,
                              hipStream_t stream) {
  (void)in_sizes; (void)n_in; (void)out_size; (void)ws_size;
  const float* x = (const float*)d_in[0];       // [16,64,56,56]
  const float* kernels = (const float*)d_in[1]; // [128,576]
  const float* a = (const float*)d_in[2];       // [581]
  const float* b = (const float*)d_in[3];       // scalar
  float* out = (float*)d_out;                   // [16,128,56,56] fp32

  char* ws = (char*)d_ws;
  int* rbucket = (int*)ws;                            // 512 B
  int* hist_partial = (int*)(ws + 512);               // 196*8*4 = 6272 B
  ushort_t* w2 = (ushort_t*)(ws + 8192);              // 147456 B
  float* tbuf = (float*)(ws + 8192 + 147456);         // 16*9*3136*4 = 1806336 B
  ushort_t* xpad = (ushort_t*)(ws + 8192 + 147456 + 1806336); // 6889472 B

  pad_kernel<<<211, 256, 0, stream>>>(x, xpad);
  tstage_kernel<<<VBLOCKS, 256, 0, stream>>>(x, a, tbuf);
  vote2_kernel<<<VBLOCKS, 256, 0, stream>>>(tbuf, a, b, hist_partial);
  w2row_kernel<<<OC, 256, 0, stream>>>(kernels, a, b, w2, rbucket);
  gemm_kernel<<<NPIX / 64, 256, 0, stream>>>(w2, xpad, hist_partial, rbucket, out);
}

// Round 6
// 109.164 us; speedup vs baseline: 2.2502x; 1.1171x over previous
//
#include <hip/hip_runtime.h>
#include <math.h>

#define IC 64
#define OC 128
#define HH 56
#define WW 56
#define BATCH 16
#define HP 58              // padded spatial
#define HW (HH*WW)         // 3136
#define NPIX (BATCH*HW)    // 50176
#define SPAN 576
#define TSIZE 8
#define PADBLK 211         // pad role blocks
#define VBANDS 28          // 2-row bands per image
#define VBLOCKS (BATCH*VBANDS)          // 448
#define NBLK1 (PADBLK + VBLOCKS + OC)   // 211+448+128 = 787

typedef unsigned short ushort_t;
typedef unsigned int uint_t;
typedef __attribute__((ext_vector_type(8))) __bf16 bf16x8;
typedef __attribute__((ext_vector_type(4))) float f32x4;

__device__ __forceinline__ ushort_t bf16_rne(float f) {
  uint_t u = __builtin_bit_cast(uint_t, f);
  u += 0x7FFFu + ((u >> 16) & 1u);
  return (ushort_t)(u >> 16);
}

// ---- kernel 1: fused prep, role-split by blockIdx ---------------------------
// [0,211):   pad — NCHW fp32 -> padded NHWC bf16
// [211,659): vote — per 2-row band: t into LDS (with halo), 9-tap gather,
//            bucket, per-block 8-bin histogram (no global atomics)
// [659,787): w2row — per-row dot/norm -> rbucket + bf16 (tap,c)-major repack
__global__ __launch_bounds__(256)
void prep_kernel(const float* __restrict__ x, const float* __restrict__ kernels,
                 const float* __restrict__ a, const float* __restrict__ bptr,
                 ushort_t* __restrict__ xpad, ushort_t* __restrict__ w2,
                 int* __restrict__ rbucket, int* __restrict__ hist_partial) {
  __shared__ float tl[224 * 9];     // 4 rows x 56 cols x 9 taps
  __shared__ int hist[TSIZE];
  __shared__ float red0[256], red1[256];
  const int bx = blockIdx.x, t = threadIdx.x;

  if (bx < PADBLK) {
    // ---------------- pad role ----------------
    int idx = bx * 256 + t;
    if (idx >= BATCH * HP * HP) return;
    int b = idx / (HP * HP);
    int rem = idx % (HP * HP);
    int y = rem / HP, xw = rem % HP;
    int h = y - 1, w = xw - 1;
    bool inb = ((unsigned)h < (unsigned)HH) && ((unsigned)w < (unsigned)WW);
    const float* src = x + (size_t)b * IC * HW + (inb ? h * WW + w : 0);
    uint_t* dst = (uint_t*)(xpad + (size_t)idx * IC);
    #pragma unroll
    for (int c2 = 0; c2 < IC / 2; ++c2) {
      float f0 = inb ? src[(2 * c2) * HW] : 0.0f;
      float f1 = inb ? src[(2 * c2 + 1) * HW] : 0.0f;
      dst[c2] = (uint_t)bf16_rne(f0) | ((uint_t)bf16_rne(f1) << 16);
    }
  } else if (bx < PADBLK + VBLOCKS) {
    // ---------------- vote role ----------------
    const int vb = bx - PADBLK;
    const int b = vb / VBANDS, band = vb % VBANDS;
    const int r0 = band * 2;
    if (t < TSIZE) hist[t] = 0;
    if (t < 224) {
      int prow = r0 - 1 + t / 56;   // -1 .. 56 (1-row halo each side)
      int col = t % 56;
      float t9[9] = {0, 0, 0, 0, 0, 0, 0, 0, 0};
      if ((unsigned)prow < (unsigned)HH) {
        const float* xb = x + (size_t)b * IC * HW + prow * WW + col;
        #pragma unroll
        for (int c = 0; c < IC; ++c) {
          float xv = xb[(size_t)c * HW];
          #pragma unroll
          for (int tap = 0; tap < 9; ++tap) t9[tap] += a[c * 9 + tap] * xv;
        }
      }
      #pragma unroll
      for (int tap = 0; tap < 9; ++tap) tl[t * 9 + tap] = t9[tap];
    }
    __syncthreads();
    if (t < 112) {
      int lr = t / 56;              // row within band (0..1)
      int col = t % 56;
      float v = 0.0f;
      #pragma unroll
      for (int kh = 0; kh < 3; ++kh) {
        int gr = r0 + lr - 1 + kh;  // global source row
        #pragma unroll
        for (int kw = 0; kw < 3; ++kw) {
          int cc = col - 1 + kw;
          if ((unsigned)gr < (unsigned)HH && (unsigned)cc < (unsigned)WW)
            v += tl[((lr + kh) * 56 + cc) * 9 + (kh * 3 + kw)];
        }
      }
      float tail = 0.5f * (a[576] + a[577] + a[578] + a[579] + a[580]);
      int hi = (int)floorf((v + tail + bptr[0]) / 2.5f);
      int r = hi % TSIZE;
      if (r < 0) r = -r;
      atomicAdd(&hist[r], 1);       // LDS atomic, 8 bins
    }
    __syncthreads();
    if (t < TSIZE) hist_partial[vb * TSIZE + t] = hist[t];
  } else {
    // ---------------- w2row role ----------------
    const int r = bx - (PADBLK + VBLOCKS);
    const float* row = kernels + (size_t)r * SPAN;
    float d = 0.0f, n2 = 0.0f;
    #pragma unroll
    for (int k0 = 0; k0 < 3; ++k0) {
      int k = k0 * 256 + t;
      if (k < SPAN) { float kv = row[k]; d += kv * a[k]; n2 += kv * kv; }
    }
    red0[t] = d; red1[t] = n2;
    __syncthreads();
    for (int s = 128; s > 0; s >>= 1) {
      if (t < s) { red0[t] += red0[t + s]; red1[t] += red1[t + s]; }
      __syncthreads();
    }
    if (t == 0) {
      float hk = red0[0], p = red1[0];
      #pragma unroll
      for (int i = 0; i < 5; ++i) { hk += p * a[SPAN + i]; p = p * p; }
      int hi = (int)floorf((hk + bptr[0]) / 2.5f);
      int rr = hi % TSIZE;
      if (rr < 0) rr = -rr;
      rbucket[r] = rr;
    }
    #pragma unroll
    for (int j0 = 0; j0 < 3; ++j0) {
      int j = j0 * 256 + t;
      if (j < SPAN) {
        int tap = j >> 6, c = j & 63;
        w2[(size_t)r * SPAN + j] = bf16_rne(row[c * 9 + tap]);
      }
    }
  }
}

// ---- kernel 2: implicit GEMM, 128x64 tile, BK=64 (one tap) ------------------
__global__ __launch_bounds__(256, 4)
void gemm_kernel(const ushort_t* __restrict__ w2, const ushort_t* __restrict__ xpad,
                 const int* __restrict__ hist_partial, const int* __restrict__ rbucket,
                 float* __restrict__ out) {
  __shared__ ushort_t As[128 * 64];   // 16 KB
  __shared__ ushort_t Bs[64 * 64];    //  8 KB
  __shared__ float factor_s[OC];
  __shared__ int counts_s[TSIZE];
  __shared__ int cnt_w[4];
  const int tid = threadIdx.x;
  const int wave = tid >> 6, lane = tid & 63;
  const int n0 = blockIdx.x * 64;
  const int wm = wave * 32;

  const int srow = lane >> 3;
  const int sch = (lane & 7) ^ srow;

  int agbase[4], bgbase[2];
  #pragma unroll
  for (int i = 0; i < 4; ++i) {
    int row = wm + i * 8 + srow;
    agbase[i] = row * SPAN + sch * 8;
  }
  #pragma unroll
  for (int i = 0; i < 2; ++i) {
    int brow = wave * 16 + i * 8 + srow;
    int n = n0 + brow;
    int b = n / HW;
    int rem = n % HW;
    int h = rem / WW, w = rem % WW;
    bgbase[i] = ((b * HP + h) * HP + w) * IC + sch * 8;
  }

  f32x4 acc[2][4] = {};

  for (int tap = 0; tap < 9; ++tap) {
    const int kh = tap / 3, kw = tap % 3;
    const int toffA = tap * 64;
    const int toffB = (kh * HP + kw) * IC;
    __syncthreads();
    #pragma unroll
    for (int i = 0; i < 4; ++i)
      __builtin_amdgcn_global_load_lds(
          (const __attribute__((address_space(1))) void*)(w2 + agbase[i] + toffA),
          (__attribute__((address_space(3))) void*)(As + (wm + i * 8) * 64), 16, 0, 0);
    #pragma unroll
    for (int i = 0; i < 2; ++i)
      __builtin_amdgcn_global_load_lds(
          (const __attribute__((address_space(1))) void*)(xpad + bgbase[i] + toffB),
          (__attribute__((address_space(3))) void*)(Bs + (wave * 16 + i * 8) * 64), 16, 0, 0);
    __syncthreads();
    #pragma unroll
    for (int kk = 0; kk < 2; ++kk) {
      const int jf = kk * 4 + (lane >> 4);
      bf16x8 af[2], bfr[4];
      #pragma unroll
      for (int m = 0; m < 2; ++m) {
        int row = wm + m * 16 + (lane & 15);
        int slot = row * 8 + (jf ^ (row & 7));
        af[m] = *(const bf16x8*)(As + slot * 8);
      }
      #pragma unroll
      for (int n = 0; n < 4; ++n) {
        int col = n * 16 + (lane & 15);
        int slot = col * 8 + (jf ^ (col & 7));
        bfr[n] = *(const bf16x8*)(Bs + slot * 8);
      }
      #pragma unroll
      for (int m = 0; m < 2; ++m)
        #pragma unroll
        for (int n = 0; n < 4; ++n)
          acc[m][n] = __builtin_amdgcn_mfma_f32_16x16x32_bf16(af[m], bfr[n], acc[m][n], 0, 0, 0);
    }
  }

  // ---- reduce hist_partial -> counts_s ----
  if (tid < TSIZE) counts_s[tid] = 0;
  __syncthreads();
  {
    int bin = tid >> 5;
    int s = 0;
    for (int k = (tid & 31); k < VBLOCKS; k += 32) s += hist_partial[k * TSIZE + bin];
    atomicAdd(&counts_s[bin], s);
  }
  __syncthreads();
  int best = counts_s[0], bi = 0;
  #pragma unroll
  for (int i = 1; i < TSIZE; ++i) { int c = counts_s[i]; if (c > best) { best = c; bi = i; } }
  int isin = (tid < OC) ? ((rbucket[tid] == bi) ? 1 : 0) : 0;
  unsigned long long bal = __ballot(isin != 0);
  if (lane == 0) cnt_w[wave] = __popcll(bal);
  __syncthreads();
  int cnt = cnt_w[0] + cnt_w[1] + cnt_w[2] + cnt_w[3];
  if (tid < OC)
    factor_s[tid] = (cnt > 0) ? (isin ? 128.0f / (float)cnt : 0.0f) : 1.0f;
  __syncthreads();

  #pragma unroll
  for (int n = 0; n < 4; ++n) {
    int np = n0 + n * 16 + (lane & 15);
    int b = np / HW;
    int rem = np % HW;
    float* obase = out + ((size_t)b * OC) * HW + rem;
    #pragma unroll
    for (int m = 0; m < 2; ++m) {
      int ocb = wm + m * 16 + (lane >> 4) * 4;
      #pragma unroll
      for (int r = 0; r < 4; ++r) {
        obase[(size_t)(ocb + r) * HW] = acc[m][n][r] * factor_s[ocb + r];
      }
    }
  }
}

extern "C" void kernel_launch(void* const* d_in, const int* in_sizes, int n_in,
                              void* d_out, int out_size, void* d_ws, size_t ws_size,
                              hipStream_t stream) {
  (void)in_sizes; (void)n_in; (void)out_size; (void)ws_size;
  const float* x = (const float*)d_in[0];       // [16,64,56,56]
  const float* kernels = (const float*)d_in[1]; // [128,576]
  const float* a = (const float*)d_in[2];       // [581]
  const float* b = (const float*)d_in[3];       // scalar
  float* out = (float*)d_out;                   // [16,128,56,56] fp32

  char* ws = (char*)d_ws;
  int* rbucket = (int*)ws;                      // 512 B
  int* hist_partial = (int*)(ws + 512);         // 448*8*4 = 14336 B
  ushort_t* w2 = (ushort_t*)(ws + 16384);       // 147456 B
  ushort_t* xpad = (ushort_t*)(ws + 16384 + 147456); // 6889472 B

  prep_kernel<<<NBLK1, 256, 0, stream>>>(x, kernels, a, b, xpad, w2, rbucket, hist_partial);
  gemm_kernel<<<NPIX / 64, 256, 0, stream>>>(w2, xpad, hist_partial, rbucket, out);
}